// Round 14
// baseline (136.231 us; speedup 1.0000x reference)
//
#include <hip/hip_runtime.h>

#define BATCH 128
#define M 259
#define D 512
#define T 256
#define NM (BATCH * M)          // 33152
#define OUTHALF (BATCH * T * D)
#define HB 130                  // half of M (130+129)
#define PAD 160                 // padded half (2 x 80 wave strips)
#define PR 320                  // LDS panel rows = A-half(160) + B-half(160)
#define BK 64

typedef __bf16 bf16;
typedef __bf16 bf16x4 __attribute__((ext_vector_type(4)));
typedef __bf16 bf16x8 __attribute__((ext_vector_type(8)));
typedef float f32x4 __attribute__((ext_vector_type(4)));

// ws float layout: wcol[NM] | wrow[NM]

// ---------------- Kernel 0: zero both accumulators -------------------------
__global__ void k_zero(float4* __restrict__ ws4) {
    int i = blockIdx.x * 256 + threadIdx.x;
    if (i < (2 * NM + 3) / 4) ws4[i] = make_float4(0.f, 0.f, 0.f, 0.f);
}

// ---------------- Kernel 1: quadrant-panel MFMA + fused norms + sums -------
// One WG per (batch, i-half, j-half): 512 WGs x 256 threads, 2 WGs/CU
// co-resident. 4 waves (2x2) of 80x80 output each (5x5 16x16 frags, proven).
// Panel: A-half rows [0,160) + B-half rows [160,320), 64 cols/slice, 40 KB.
__launch_bounds__(256)
__global__ void k_pairs(const float* __restrict__ x1, const float* __restrict__ x2,
                        float* __restrict__ ws) {
    __shared__ __align__(16) bf16 P[PR * BK];   // 40 KB
    __shared__ float nrm[PR];

    int s   = blockIdx.x;                 // 512 = 8 * 64, bijective XCD swizzle
    int bid = (s & 7) * 64 + (s >> 3);
    int b   = bid >> 2;
    int ih  = (bid >> 1) & 1;
    int jh  = bid & 1;
    int i0  = ih * HB;
    int j0  = jh * HB;

    int t    = threadIdx.x;
    int lane = t & 63;
    int w    = t >> 6;                    // 0..3
    int wm   = w >> 1, wn = w & 1;        // 2x2 wave grid, 80x80 per wave

    const float* Ab = x1 + (size_t)b * M * D;
    const float* Bb = x2 + (size_t)b * M * D;

    // staging map: 320 rows x 16 float4-cols; thread t covers rows q+16p,
    // f4-col c4f; p<10 = A-half (local row), p>=10 = B-half (row-160).
    int q = t >> 4, c4f = t & 15;
    int off[20], wro[20];
#pragma unroll
    for (int p = 0; p < 20; ++p) {
        int row  = q + 16 * p;            // [0,320)
        int grow = (p < 10) ? min(i0 + row, M - 1)
                            : min(j0 + (row - PAD), M - 1);
        off[p] = grow * D + c4f * 4;
        wro[p] = row * BK + (((c4f >> 1) ^ (row & 7)) << 3) + (t & 1) * 4;
    }

    // fragment read offsets (proven swizzle-matched formula)
    int a_off[5][2], b_off[5][2];
#pragma unroll
    for (int f = 0; f < 5; ++f) {
        int rowa = wm * 80 + f * 16 + (lane & 15);
        int rowb = PAD + wn * 80 + f * 16 + (lane & 15);
#pragma unroll
        for (int kk = 0; kk < 2; ++kk) {
            int slot = kk * 4 + (lane >> 4);
            a_off[f][kk] = rowa * BK + ((slot ^ (rowa & 7)) << 3);
            b_off[f][kk] = rowb * BK + ((slot ^ (rowb & 7)) << 3);
        }
    }

    f32x4 acc[5][5];
#pragma unroll
    for (int fi = 0; fi < 5; ++fi)
#pragma unroll
        for (int fj = 0; fj < 5; ++fj) acc[fi][fj] = (f32x4)0.f;

    float sa[20];
#pragma unroll
    for (int p = 0; p < 20; ++p) sa[p] = 0.f;

#define STAGE5(P0, BASE) do {                                                   \
        float4 v_[5];                                                           \
        _Pragma("unroll")                                                       \
        for (int i_ = 0; i_ < 5; ++i_)                                          \
            v_[i_] = *(const float4*)((BASE) + off[(P0) + i_] + k0);            \
        _Pragma("unroll")                                                       \
        for (int i_ = 0; i_ < 5; ++i_) {                                        \
            sa[(P0) + i_] += v_[i_].x * v_[i_].x + v_[i_].y * v_[i_].y          \
                           + v_[i_].z * v_[i_].z + v_[i_].w * v_[i_].w;         \
            *(bf16x4*)&P[wro[(P0) + i_]] = bf16x4{ (bf16)v_[i_].x,              \
                (bf16)v_[i_].y, (bf16)v_[i_].z, (bf16)v_[i_].w };               \
        } } while (0)

    for (int k0 = 0; k0 < D; k0 += BK) {
        __syncthreads();            // prev slice's LDS reads complete
        STAGE5(0,  Ab);             // A-half rows 0..79
        STAGE5(5,  Ab);             // A-half rows 80..159
        STAGE5(10, Bb);             // B-half rows 0..79
        STAGE5(15, Bb);             // B-half rows 80..159
        __syncthreads();            // panel visible
#pragma unroll
        for (int kk = 0; kk < 2; ++kk) {
            bf16x8 af[5], bfr[5];
#pragma unroll
            for (int f = 0; f < 5; ++f) af[f]  = *(const bf16x8*)&P[a_off[f][kk]];
#pragma unroll
            for (int f = 0; f < 5; ++f) bfr[f] = *(const bf16x8*)&P[b_off[f][kk]];
#pragma unroll
            for (int fi = 0; fi < 5; ++fi)
#pragma unroll
                for (int fj = 0; fj < 5; ++fj)
                    acc[fi][fj] = __builtin_amdgcn_mfma_f32_16x16x32_bf16(
                        af[fi], bfr[fj], acc[fi][fj], 0, 0, 0);
        }
    }
#undef STAGE5

    // norms: reduce each staged row over its 16 covering lanes -> nrm[]
#pragma unroll
    for (int p = 0; p < 20; ++p) {
        float v = sa[p];
        v += __shfl_xor(v, 1); v += __shfl_xor(v, 2);
        v += __shfl_xor(v, 4); v += __shfl_xor(v, 8);
        if ((t & 15) == 0) nrm[q + 16 * p] = v;
    }
    __syncthreads();

    // epilogue: A_ij = 1/(1+dist), masked; row/col partial sums
    float na_[5][4], nb_[5];
#pragma unroll
    for (int f = 0; f < 5; ++f) {
#pragma unroll
        for (int r = 0; r < 4; ++r)
            na_[f][r] = nrm[wm * 80 + f * 16 + (lane >> 4) * 4 + r];
        nb_[f] = nrm[PAD + wn * 80 + f * 16 + (lane & 15)];
    }

    float rs[5][4], cs[5];
#pragma unroll
    for (int f = 0; f < 5; ++f) {
#pragma unroll
        for (int r = 0; r < 4; ++r) rs[f][r] = 0.f;
        cs[f] = 0.f;
    }

#pragma unroll
    for (int fi = 0; fi < 5; ++fi) {
#pragma unroll
        for (int fj = 0; fj < 5; ++fj) {
#pragma unroll
            for (int r = 0; r < 4; ++r) {
                int il = wm * 80 + fi * 16 + (lane >> 4) * 4 + r;
                int jl = wn * 80 + fj * 16 + (lane & 15);
                int ig = i0 + il, jg = j0 + jl;
                float av = 0.f;
                if (il < HB && ig < M && jl < HB && jg < M) {
                    float sq   = na_[fi][r] + nb_[fj] - 2.f * acc[fi][fj][r];
                    float dist = sqrtf(fmaxf(sq, 0.f));
                    av = 1.f / (1.f + dist);
                }
                rs[fi][r] += av;
                cs[fj]    += av;
            }
        }
    }

    int b_off_w = b * M;
    // wrow (sum over j): reduce over lane&15 -> global atomic
#pragma unroll
    for (int f = 0; f < 5; ++f)
#pragma unroll
        for (int r = 0; r < 4; ++r) {
            float v = rs[f][r];
            v += __shfl_xor(v, 1); v += __shfl_xor(v, 2);
            v += __shfl_xor(v, 4); v += __shfl_xor(v, 8);
            int il = wm * 80 + f * 16 + (lane >> 4) * 4 + r;
            int ig = i0 + il;
            if ((lane & 15) == 0 && il < HB && ig < M)
                atomicAdd(&ws[NM + b_off_w + ig], v);
        }
    // wcol (sum over i): reduce over lane>>4 -> global atomic
#pragma unroll
    for (int f = 0; f < 5; ++f) {
        float v = cs[f];
        v += __shfl_xor(v, 16); v += __shfl_xor(v, 32);
        int jl = wn * 80 + f * 16 + (lane & 15);
        int jg = j0 + jl;
        if ((lane >> 4) == 0 && jl < HB && jg < M)
            atomicAdd(&ws[b_off_w + jg], v);
    }
}

// ---------------- Kernel 2: sliding-window weighted sum (float4, proven) ---
__global__ void k_out(const float* __restrict__ x1, const float* __restrict__ x2,
                      const float* __restrict__ ws, float* __restrict__ out) {
    int bid   = blockIdx.x;
    int which = bid & 1;
    int tc    = (bid >> 1) & 7;
    int b     = bid >> 4;
    int d4    = threadIdx.x << 2;
    const float* src  = which ? x2 : x1;
    const float* wgt  = ws + (which ? NM : 0) + b * M;
    const float* rows = src + (size_t)b * M * D + d4;
    float* o = out + (size_t)which * OUTHALF + ((size_t)b * T + tc * 32) * D + d4;
    int t0 = tc * 32;
    float4 v0 = *(const float4*)(rows + (size_t)(t0 + 0) * D);
    float4 v1 = *(const float4*)(rows + (size_t)(t0 + 1) * D);
    float4 v2 = *(const float4*)(rows + (size_t)(t0 + 2) * D);
    float s0 = wgt[t0 + 0], s1 = wgt[t0 + 1], s2 = wgt[t0 + 2];
#pragma unroll 4
    for (int tt = 0; tt < 32; ++tt) {
        float4 v3 = *(const float4*)(rows + (size_t)(t0 + tt + 3) * D);
        float s3  = wgt[t0 + tt + 3];
        float4 r;
        r.x = s0 * v0.x + s1 * v1.x + s2 * v2.x + s3 * v3.x;
        r.y = s0 * v0.y + s1 * v1.y + s2 * v2.y + s3 * v3.y;
        r.z = s0 * v0.z + s1 * v1.z + s2 * v2.z + s3 * v3.z;
        r.w = s0 * v0.w + s1 * v1.w + s2 * v2.w + s3 * v3.w;
        *(float4*)(o + (size_t)tt * D) = r;
        v0 = v1; v1 = v2; v2 = v3;
        s0 = s1; s1 = s2; s2 = s3;
    }
}

extern "C" void kernel_launch(void* const* d_in, const int* in_sizes, int n_in,
                              void* d_out, int out_size, void* d_ws, size_t ws_size,
                              hipStream_t stream) {
    const float* x1 = (const float*)d_in[0];
    const float* x2 = (const float*)d_in[1];
    float* out = (float*)d_out;
    float* ws  = (float*)d_ws;

    k_zero<<<(2 * NM / 4 + 255) / 256, 256, 0, stream>>>((float4*)ws);   // 65 blocks
    k_pairs<<<512, 256, 0, stream>>>(x1, x2, ws);                        // 2 WG/CU
    k_out<<<BATCH * 16, 128, 0, stream>>>(x1, x2, ws, out);              // 2048 blocks
}